// Round 6
// baseline (40188.657 us; speedup 1.0000x reference)
//
#include <hip/hip_runtime.h>
#include <cstdint>

// TinyVanillaRNN: T=16384 sequential steps h = tanh(U[:,x_t] + W h + bh);
// logits[t] = V h_t + by. out = [logits (T*O) | h_T (H)], fp32.
//
// R9: delete the intra-block distribution stage. R8 proved the poll reissue
// period is NOT the gate (3-deep same-address polls MSHR-merge: FETCH_SIZE
// unchanged 547->537MB, dur +6%). The remaining removable serial cost is
// R3/R8's LDS staging: poll 2 values/thread -> LDS write -> __syncthreads
// (8-wave two-phase gating) -> 4x ds_read. R9 re-maps each lane's W/V
// fragment k-set to k in {2l, 2l+1} + 128*i (i=0..7): a wave's 8 coalesced
// dwordx4 tagged-pair loads (1KB each, 8KB = all of h) then deliver EXACTLY
// the 16 h values each lane needs. No LDS, no barrier, waves free-run.
//
// Safety (no barrier, 2-parity buffer): tag t is written only after the
// writer gathered ALL of tag t-1, which required every wave to publish t-1,
// which required every wave to finish gathering t-2 -- so no wave can still
// be polling buffer[t&1] (tag t-2) when tag t overwrites it. Distance-2
// dependency, same invariant R3's barrier enforced, now enforced by the
// dataflow alone.
//
// Handoff stays on the only HW-verified low-latency path (R7 refuted the
// XCD-local sc0 scheme: stale-L1 spins, 10x slower): agent-scope relaxed
// atomic publish, sc0+sc1 16B poll loads, tag = step number packed with the
// f32 bits in one u64 (single-copy atomic at the LLC).

constexpr int T_STEPS = 16384;
constexpr int D_DIM   = 512;
constexpr int H_DIM   = 1024;
constexpr int O_DIM   = 512;
constexpr int NBLK    = 32;
constexpr int NTHR    = 512;

typedef unsigned int u32x4 __attribute__((ext_vector_type(4)));

__device__ __forceinline__ float fast_tanh(float x) {
    // 1 - 2/(e^{2x}+1); saturates exactly at +-1 for large |x|
    float e = __expf(2.f * x);
    return 1.f - 2.f / (e + 1.f);
}

// Issue one 16B tagged-pair load observing the LLC (sc0 sc1), no wait.
#define POLL_ISSUE(reg, addr)                                          \
    asm volatile("global_load_dwordx4 %0, %1, off sc0 sc1"             \
                 : "=v"(reg) : "v"((unsigned long long)(addr)))

__global__ __launch_bounds__(NTHR, 1)
void rnn_fused(const int* __restrict__ xs, const float* __restrict__ h0,
               const float* __restrict__ U, const float* __restrict__ W,
               const float* __restrict__ V, const float* __restrict__ bh,
               const float* __restrict__ by, float* __restrict__ out,
               unsigned long long* __restrict__ htag)
{
    const int b   = blockIdx.x;
    const int tid = threadIdx.x;
    const int w   = tid >> 6;      // wave 0..7
    const int l   = tid & 63;      // lane

    // ---- W fragment: rows wr0..wr0+3, k in {2l,2l+1}+128i (i=0..7) ----
    // Union over 64 lanes covers k=0..1023 exactly once; butterfly reduce
    // is k-map independent.
    const int wr0 = b * 32 + w * 4;
    float2 wreg[4][8];
#pragma unroll
    for (int j = 0; j < 4; ++j)
#pragma unroll
        for (int i = 0; i < 8; ++i)
            wreg[j][i] = *(const float2*)(W + (size_t)(wr0 + j) * H_DIM + 128 * i + 2 * l);
    const float bh_r = bh[wr0 + (l & 3)];
    const int   urow = wr0 + (l & 3);

    // ---- V fragment: rows vr0, vr0+1, same k-set ----
    const int vr0 = b * 16 + w * 2;
    float2 vreg[2][8];
#pragma unroll
    for (int m = 0; m < 2; ++m)
#pragma unroll
        for (int i = 0; i < 8; ++i)
            vreg[m][i] = *(const float2*)(V + (size_t)(vr0 + m) * H_DIM + 128 * i + 2 * l);
    const float by_r = by[vr0 + (l & 1)];

    // Per-parity gather bases: lane l's quad i sits at u64 index 128i + 2l
    // (byte 1024i + 16l) -> a wave's load i is a fully-coalesced 1KB read.
    const unsigned long long* gp0 = htag + 2 * l;
    const unsigned long long* gp1 = htag + H_DIM + 2 * l;

    const bool o1 = (l & 1) != 0, o2 = (l & 2) != 0;

    float2 h2[8];

    for (int t = 0; t < T_STEPS; ++t) {
        // independent prefetch chain: xs[t] -> U gather (overlaps the poll)
        const int   xt = xs[t];
        const float uv = U[(size_t)urow * D_DIM + xt];

        // ---- acquire h^{(t)}: gather all 16 needed values directly ----
        if (t == 0) {
#pragma unroll
            for (int i = 0; i < 8; ++i)
                h2[i] = *(const float2*)(h0 + 128 * i + 2 * l);
        } else {
            const unsigned long long* pp = ((t - 1) & 1) ? gp1 : gp0;
            const unsigned want = (unsigned)(t - 1);
            u32x4 q[8];
            for (;;) {
#pragma unroll
                for (int i = 0; i < 8; ++i) POLL_ISSUE(q[i], pp + 128 * i);
                asm volatile("s_waitcnt vmcnt(0)" ::: "memory");
                __builtin_amdgcn_sched_barrier(0);
                bool ok = true;
#pragma unroll
                for (int i = 0; i < 8; ++i)
                    ok = ok && (q[i].y == want) && (q[i].w == want);
                if (__all(ok)) break;
            }
#pragma unroll
            for (int i = 0; i < 8; ++i)
                h2[i] = make_float2(__uint_as_float(q[i].x),
                                    __uint_as_float(q[i].z));
        }

        // ---- critical path: 64 FMAs + fused select+butterfly reduce ----
        float2 a0 = {0.f, 0.f}, a1 = {0.f, 0.f}, a2 = {0.f, 0.f}, a3 = {0.f, 0.f};
#pragma unroll
        for (int i = 0; i < 8; ++i) {
            a0.x += wreg[0][i].x * h2[i].x; a0.y += wreg[0][i].y * h2[i].y;
            a1.x += wreg[1][i].x * h2[i].x; a1.y += wreg[1][i].y * h2[i].y;
            a2.x += wreg[2][i].x * h2[i].x; a2.y += wreg[2][i].y * h2[i].y;
            a3.x += wreg[3][i].x * h2[i].x; a3.y += wreg[3][i].y * h2[i].y;
        }
        const float s0 = a0.x + a0.y, s1 = a1.x + a1.y;
        const float s2 = a2.x + a2.y, s3 = a3.x + a3.y;

        // select+butterfly: lane l ends with full sum of row wr0 + (l&3)
        float A  = o1 ? s1 : s0, Ax = o1 ? s0 : s1;
        float B  = o1 ? s3 : s2, Bx = o1 ? s2 : s3;
        A += __shfl_xor(Ax, 1);
        B += __shfl_xor(Bx, 1);
        float Cv = o2 ? B : A, Cx = o2 ? A : B;
        Cv += __shfl_xor(Cx, 2);
        Cv += __shfl_xor(Cv, 4);
        Cv += __shfl_xor(Cv, 8);
        Cv += __shfl_xor(Cv, 16);
        Cv += __shfl_xor(Cv, 32);

        const float hv = fast_tanh(Cv + bh_r + uv);
        if (l < 4) {
            const unsigned long long pk =
                ((unsigned long long)(unsigned)t << 32) |
                (unsigned long long)__float_as_uint(hv);
            __hip_atomic_store(htag + (size_t)(t & 1) * H_DIM + wr0 + l, pk,
                               __ATOMIC_RELAXED, __HIP_MEMORY_SCOPE_AGENT);
        }
        __builtin_amdgcn_sched_barrier(0);   // publish must not sink below V

        // ---- hidden window: logits[t-1] from h2 registers (h^{(t)}) ----
        if (t > 0) {
            float2 p0 = {0.f, 0.f}, p1 = {0.f, 0.f};
#pragma unroll
            for (int i = 0; i < 8; ++i) {
                p0.x += vreg[0][i].x * h2[i].x; p0.y += vreg[0][i].y * h2[i].y;
                p1.x += vreg[1][i].x * h2[i].x; p1.y += vreg[1][i].y * h2[i].y;
            }
            const float sv0 = p0.x + p0.y, sv1 = p1.x + p1.y;
            float P  = o1 ? sv1 : sv0, Px = o1 ? sv0 : sv1;
            P += __shfl_xor(Px, 1);
            P += __shfl_xor(P, 2);
            P += __shfl_xor(P, 4);
            P += __shfl_xor(P, 8);
            P += __shfl_xor(P, 16);
            P += __shfl_xor(P, 32);
            if (l < 2) out[(size_t)(t - 1) * O_DIM + vr0 + l] = P + by_r;
        }
    }

    // ---- epilogue: h_T (tag T-1, parity 1) -> out tail + logits[T-1] ----
    {
        const unsigned long long* pp = gp1;         // (T-1)&1 == 1
        const unsigned want = (unsigned)(T_STEPS - 1);
        u32x4 q[8];
        for (;;) {
#pragma unroll
            for (int i = 0; i < 8; ++i) POLL_ISSUE(q[i], pp + 128 * i);
            asm volatile("s_waitcnt vmcnt(0)" ::: "memory");
            __builtin_amdgcn_sched_barrier(0);
            bool ok = true;
#pragma unroll
            for (int i = 0; i < 8; ++i)
                ok = ok && (q[i].y == want) && (q[i].w == want);
            if (__all(ok)) break;
        }
#pragma unroll
        for (int i = 0; i < 8; ++i)
            h2[i] = make_float2(__uint_as_float(q[i].x),
                                __uint_as_float(q[i].z));

        if (b == 0 && w == 0) {
#pragma unroll
            for (int i = 0; i < 8; ++i)
                *(float2*)&out[(size_t)T_STEPS * O_DIM + 128 * i + 2 * l] = h2[i];
        }

        float2 p0 = {0.f, 0.f}, p1 = {0.f, 0.f};
#pragma unroll
        for (int i = 0; i < 8; ++i) {
            p0.x += vreg[0][i].x * h2[i].x; p0.y += vreg[0][i].y * h2[i].y;
            p1.x += vreg[1][i].x * h2[i].x; p1.y += vreg[1][i].y * h2[i].y;
        }
        const float sv0 = p0.x + p0.y, sv1 = p1.x + p1.y;
        float P  = o1 ? sv1 : sv0, Px = o1 ? sv0 : sv1;
        P += __shfl_xor(Px, 1);
        P += __shfl_xor(P, 2);
        P += __shfl_xor(P, 4);
        P += __shfl_xor(P, 8);
        P += __shfl_xor(P, 16);
        P += __shfl_xor(P, 32);
        if (l < 2) out[(size_t)(T_STEPS - 1) * O_DIM + vr0 + l] = P + by_r;
    }
}

extern "C" void kernel_launch(void* const* d_in, const int* in_sizes, int n_in,
                              void* d_out, int out_size, void* d_ws, size_t ws_size,
                              hipStream_t stream) {
    const int*   xs = (const int*)d_in[0];
    const float* h0 = (const float*)d_in[1];
    const float* U  = (const float*)d_in[2];
    const float* W  = (const float*)d_in[3];
    const float* V  = (const float*)d_in[4];
    const float* bh = (const float*)d_in[5];
    const float* by = (const float*)d_in[6];
    float* out = (float*)d_out;

    // ws: htag[2][1024] u64. Poison tag 0xAAAAAAAA never matches a step in
    // [0,16384); memset re-runs on every graph replay, clearing stale tags.
    unsigned long long* htag = (unsigned long long*)d_ws;
    hipMemsetAsync(d_ws, 0xAA, 2 * H_DIM * sizeof(unsigned long long), stream);

    rnn_fused<<<NBLK, NTHR, 0, stream>>>(xs, h0, U, W, V, bh, by, out, htag);
}

// Round 7
// 37323.416 us; speedup vs baseline: 1.0768x; 1.0768x over previous
//
#include <hip/hip_runtime.h>
#include <cstdint>

// TinyVanillaRNN: T=16384 sequential steps h = tanh(U[:,x_t] + W h + bh);
// logits[t] = V h_t + by. out = [logits (T*O) | h_T (H)], fp32.
//
// R10 = R3 (proven 22865us) + poll PRELOAD. Refutation ledger:
//   R7: XCD-local sc0 polling -> stale-L1 spins, 10x slower. Agent-scope
//       (sc0+sc1 at the LLC) is the only low-latency visibility path.
//   R8: 3-deep same-address poll pipeline -> MSHR-merged, no gain (+6%).
//   R9: no-LDS full-vector per-wave gather -> 8x poll footprint, LLC
//       congestion, 2-3x slower with heavy variance.
// => R3's topology (per-thread 16B poll + LDS distribute) is right; the
// remaining serial term is ORDER: R3 issued the first poll for t+1 after
// the logits matvec, so detect = logits + full RTT. R10 issues the 16B
// tagged-pair load immediately after publish(t), computes logits while it
// flies, then waits+checks. Single 16B load (snapshot atomicity validated
// by R8's pass) replaces R3's two 8B atomic loads; reload loop otherwise
// identical. U-gather moved after the acquire so the check's vmcnt(0)
// never waits on it (it hides under LDS+barrier+matvec instead).
//
// Everything else is R3 verbatim: 32 blocks x 512 threads; thread = 4
// W-rows x 16 k's (64 W floats in VGPRs); swizzled LDS h distribute (4x
// ds_read_b128); fused select+butterfly reduce; tagged u64 handoff with
// parity double-buffer; agent-scope relaxed publish.

constexpr int T_STEPS = 16384;
constexpr int D_DIM   = 512;
constexpr int H_DIM   = 1024;
constexpr int O_DIM   = 512;
constexpr int NBLK    = 32;
constexpr int NTHR    = 512;

typedef unsigned int u32x4 __attribute__((ext_vector_type(4)));

__device__ __forceinline__ float fast_tanh(float x) {
    // 1 - 2/(e^{2x}+1); saturates exactly at +-1 for large |x|
    float e = __expf(2.f * x);
    return 1.f - 2.f / (e + 1.f);
}

__device__ __forceinline__ float hsum4(const float4& v) {
    return (v.x + v.y) + (v.z + v.w);
}

// Issue one 16B tagged-pair load observing the LLC (sc0 sc1); no wait here.
#define POLL_ISSUE(reg, addr)                                          \
    asm volatile("global_load_dwordx4 %0, %1, off sc0 sc1"             \
                 : "=v"(reg) : "v"((unsigned long long)(addr)))

#define WAIT_VM0()                                                     \
    do {                                                               \
        asm volatile("s_waitcnt vmcnt(0)" ::: "memory");               \
        __builtin_amdgcn_sched_barrier(0);                             \
    } while (0)

__global__ __launch_bounds__(NTHR, 2)
void rnn_fused(const int* __restrict__ xs, const float* __restrict__ h0,
               const float* __restrict__ U, const float* __restrict__ W,
               const float* __restrict__ V, const float* __restrict__ bh,
               const float* __restrict__ by, float* __restrict__ out,
               unsigned long long* __restrict__ htag)
{
    const int b   = blockIdx.x;
    const int tid = threadIdx.x;
    const int w   = tid >> 6;      // wave 0..7
    const int l   = tid & 63;      // lane

    // h in LDS: 64 chunks x 16 floats; quad q of chunk c stored at dword
    // 16c + 4*(q ^ ((c>>1)&3)) (permutation inside the 64B chunk -> no
    // padding; spreads reads over all 32 banks).
    __shared__ float hl[2][H_DIM];

    // ---- W fragment: rows wr0..wr0+3, k in [16l, 16l+16) ----
    const int wr0 = b * 32 + w * 4;
    float4 wreg[4][4];
#pragma unroll
    for (int j = 0; j < 4; ++j)
#pragma unroll
        for (int q = 0; q < 4; ++q)
            wreg[j][q] = *(const float4*)(W + (size_t)(wr0 + j) * H_DIM + 16 * l + 4 * q);
    const float bh_r = bh[wr0 + (l & 3)];
    const int   urow = wr0 + (l & 3);

    // ---- V fragment: rows vr0, vr0+1, same k-chunk ----
    const int vr0 = b * 16 + w * 2;
    float4 vreg[2][4];
#pragma unroll
    for (int m = 0; m < 2; ++m)
#pragma unroll
        for (int q = 0; q < 4; ++q)
            vreg[m][q] = *(const float4*)(V + (size_t)(vr0 + m) * H_DIM + 16 * l + 4 * q);
    const float by_r = by[vr0 + (l & 1)];

    // ---- LDS addresses (dwords) ----
    int rdw[4];                    // lane reads chunk l, logical quads 0..3
#pragma unroll
    for (int q = 0; q < 4; ++q)
        rdw[q] = 16 * l + 4 * (q ^ ((l >> 1) & 3));
    const int c   = tid >> 3;                       // staged chunk
    const int qw  = (tid >> 1) & 3;                 // staged quad
    const int wdw = 16 * c + 4 * (qw ^ ((c >> 1) & 3)) + 2 * (tid & 1);  // 8B aligned

    const bool o1 = (l & 1) != 0, o2 = (l & 2) != 0;

    u32x4 pq;                       // preloaded tagged pair {v0,tag0,v1,tag1}

    for (int t = 0; t < T_STEPS; ++t) {
        const int sb = (~t) & 1;
        float* hb = hl[sb];

        // ---- acquire h^{(t)} ----
        float2 hpair;
        if (t == 0) {
            hpair = *(const float2*)(h0 + 2 * tid);
        } else {
            const unsigned want = (unsigned)(t - 1);
            // check the preload issued right after publish(t-1)
            WAIT_VM0();
            if (!__all(pq.y == want && pq.w == want)) {
                const unsigned long long* pp =
                    htag + (size_t)((t - 1) & 1) * H_DIM + 2 * tid;
                do {
                    POLL_ISSUE(pq, pp);
                    WAIT_VM0();
                } while (!__all(pq.y == want && pq.w == want));
            }
            hpair = make_float2(__uint_as_float(pq.x), __uint_as_float(pq.z));
        }

        // xs[t] -> U gather: issued after acquire; latency hides under
        // LDS write + barrier + ds_reads + W-matvec (~500cy to use site).
        const int   xt = xs[t];
        const float uv = U[(size_t)urow * D_DIM + xt];

        *(float2*)&hb[wdw] = hpair;
        __syncthreads();

        // ---- critical path: 16 h floats, 64 FMAs, fused select+reduce ----
        float4 h4[4];
#pragma unroll
        for (int q = 0; q < 4; ++q) h4[q] = *(const float4*)&hb[rdw[q]];

        float s[4];
#pragma unroll
        for (int j = 0; j < 4; ++j) {
            float4 a = make_float4(0.f, 0.f, 0.f, 0.f);
#pragma unroll
            for (int q = 0; q < 4; ++q) {
                a.x += wreg[j][q].x * h4[q].x;
                a.y += wreg[j][q].y * h4[q].y;
                a.z += wreg[j][q].z * h4[q].z;
                a.w += wreg[j][q].w * h4[q].w;
            }
            s[j] = hsum4(a);
        }
        // select+butterfly: lane l ends with full sum of row wr0 + (l&3)
        float A  = o1 ? s[1] : s[0], Ax = o1 ? s[0] : s[1];
        float B  = o1 ? s[3] : s[2], Bx = o1 ? s[2] : s[3];
        A += __shfl_xor(Ax, 1);
        B += __shfl_xor(Bx, 1);
        float Cv = o2 ? B : A, Cx = o2 ? A : B;
        Cv += __shfl_xor(Cx, 2);
        Cv += __shfl_xor(Cv, 4);
        Cv += __shfl_xor(Cv, 8);
        Cv += __shfl_xor(Cv, 16);
        Cv += __shfl_xor(Cv, 32);

        const float hv = fast_tanh(Cv + bh_r + uv);
        if (l < 4) {
            const unsigned long long pk =
                ((unsigned long long)(unsigned)t << 32) |
                (unsigned long long)__float_as_uint(hv);
            __hip_atomic_store(htag + (size_t)(t & 1) * H_DIM + wr0 + l, pk,
                               __ATOMIC_RELAXED, __HIP_MEMORY_SCOPE_AGENT);
        }
        __builtin_amdgcn_sched_barrier(0);   // publish before preload issue

        // ---- PRELOAD: issue the poll for tag t (parity t&1) now; it
        // flies while we compute logits. Checked at top of t+1 / epilogue.
        POLL_ISSUE(pq, htag + (size_t)(t & 1) * H_DIM + 2 * tid);
        __builtin_amdgcn_sched_barrier(0);   // keep the issue early

        // ---- hidden window: logits[t-1] from h4 registers (h^{(t)}) ----
        if (t > 0) {
            float sv[2];
#pragma unroll
            for (int m = 0; m < 2; ++m) {
                float4 a = make_float4(0.f, 0.f, 0.f, 0.f);
#pragma unroll
                for (int q = 0; q < 4; ++q) {
                    a.x += vreg[m][q].x * h4[q].x;
                    a.y += vreg[m][q].y * h4[q].y;
                    a.z += vreg[m][q].z * h4[q].z;
                    a.w += vreg[m][q].w * h4[q].w;
                }
                sv[m] = hsum4(a);
            }
            float P  = o1 ? sv[1] : sv[0], Px = o1 ? sv[0] : sv[1];
            P += __shfl_xor(Px, 1);
            P += __shfl_xor(P, 2);
            P += __shfl_xor(P, 4);
            P += __shfl_xor(P, 8);
            P += __shfl_xor(P, 16);
            P += __shfl_xor(P, 32);
            if (l < 2) out[(size_t)(t - 1) * O_DIM + vr0 + l] = P + by_r;
        }
    }

    // ---- epilogue: h_T (tag T-1, parity 1) -> out tail + logits[T-1] ----
    {
        const unsigned want = (unsigned)(T_STEPS - 1);
        // the loop's last preload targeted exactly this {parity, tag}
        WAIT_VM0();
        if (!__all(pq.y == want && pq.w == want)) {
            const unsigned long long* pp =
                htag + (size_t)((T_STEPS - 1) & 1) * H_DIM + 2 * tid;
            do {
                POLL_ISSUE(pq, pp);
                WAIT_VM0();
            } while (!__all(pq.y == want && pq.w == want));
        }
        float2 hpair = make_float2(__uint_as_float(pq.x),
                                   __uint_as_float(pq.z));
        if (b == 0)
            *(float2*)&out[(size_t)T_STEPS * O_DIM + 2 * tid] = hpair;

        float* hb = hl[1];             // free: loop's last stage used hl[0]
        *(float2*)&hb[wdw] = hpair;
        __syncthreads();
        float4 h4[4];
#pragma unroll
        for (int qq = 0; qq < 4; ++qq) h4[qq] = *(const float4*)&hb[rdw[qq]];
        float sv[2];
#pragma unroll
        for (int m = 0; m < 2; ++m) {
            float4 a = make_float4(0.f, 0.f, 0.f, 0.f);
#pragma unroll
            for (int qq = 0; qq < 4; ++qq) {
                a.x += vreg[m][qq].x * h4[qq].x;
                a.y += vreg[m][qq].y * h4[qq].y;
                a.z += vreg[m][qq].z * h4[qq].z;
                a.w += vreg[m][qq].w * h4[qq].w;
            }
            sv[m] = hsum4(a);
        }
        float P  = o1 ? sv[1] : sv[0], Px = o1 ? sv[0] : sv[1];
        P += __shfl_xor(Px, 1);
        P += __shfl_xor(P, 2);
        P += __shfl_xor(P, 4);
        P += __shfl_xor(P, 8);
        P += __shfl_xor(P, 16);
        P += __shfl_xor(P, 32);
        if (l < 2) out[(size_t)(T_STEPS - 1) * O_DIM + vr0 + l] = P + by_r;
    }
}

extern "C" void kernel_launch(void* const* d_in, const int* in_sizes, int n_in,
                              void* d_out, int out_size, void* d_ws, size_t ws_size,
                              hipStream_t stream) {
    const int*   xs = (const int*)d_in[0];
    const float* h0 = (const float*)d_in[1];
    const float* U  = (const float*)d_in[2];
    const float* W  = (const float*)d_in[3];
    const float* V  = (const float*)d_in[4];
    const float* bh = (const float*)d_in[5];
    const float* by = (const float*)d_in[6];
    float* out = (float*)d_out;

    // ws: htag[2][1024] u64. Poison tag 0xAAAAAAAA never matches a step in
    // [0,16384); memset re-runs on every graph replay, clearing stale tags.
    unsigned long long* htag = (unsigned long long*)d_ws;
    hipMemsetAsync(d_ws, 0xAA, 2 * H_DIM * sizeof(unsigned long long), stream);

    rnn_fused<<<NBLK, NTHR, 0, stream>>>(xs, h0, U, W, V, bh, by, out, htag);
}

// Round 9
// 24887.347 us; speedup vs baseline: 1.6148x; 1.4997x over previous
//
#include <hip/hip_runtime.h>
#include <cstdint>

// TinyVanillaRNN: T=16384 sequential steps h = tanh(U[:,x_t] + W h + bh);
// logits[t] = V h_t + by. out = [logits (T*O) | h_T (H)], fp32.
//
// R12 == R11 resubmitted (round 8 lost to GPUAcquisitionTimeout; R11 never
// reached hardware). R11 = R3 (proven 22865us) with two surgical trims.
// Refutation ledger:
//   R7: XCD-local sc0 polling -> stale spins, 10x worse.
//   R8: same-address poll pipelining -> MSHR-merged, +6%.
//   R9: no-LDS wide gather -> 8x poll footprint, LLC congestion, 2-3x worse.
//   R10: poll preload + U-gather after acquire -> +63%, heavy variance
//        (U latency trapped in barrier drain; higher poll pressure).
// => R3's handoff topology is locally optimal; the comm RTT (~1900cy) is
// irreducible at agent scope. R11 removes the last non-comm serial cost:
//   1. __syncthreads (full vmcnt/lgkm drain + 2-phase rendezvous) replaced
//      by an LDS arrival counter: per wave, lane 0 ds_add's after
//      lgkmcnt(0); consumers spin one volatile LDS word until
//      ctr >= 8*(t+1). No vmem drain on the critical path. Cross-step LDS
//      reuse safety: a wave reaches step t+1's write of buffer (t&1) only
//      after passing ctr >= 8(t+1), i.e. all waves arrived at step t, and
//      each arrival follows that wave's step t-1 reads of the same buffer
//      in program order -- distance-2 invariant enforced by the counter.
//   2. Poll = ONE 16B sc0|sc1 load (snapshot atomicity HW-validated by
//      R8/R10 passes) with R3's per-lane DIVERGENT exit (satisfied lanes
//      leave the exec mask; no __all whole-wave re-polls).
// Everything else is R3 verbatim: 32x512; thread = 4 W-rows x 16 k's in
// VGPRs; U-gather issued BEFORE the poll (hides under the spin); swizzled
// LDS h distribute (4x ds_read_b128); fused select+butterfly reduce;
// tagged u64 publish, parity double buffer; logits in the publish shadow.

constexpr int T_STEPS = 16384;
constexpr int D_DIM   = 512;
constexpr int H_DIM   = 1024;
constexpr int O_DIM   = 512;
constexpr int NBLK    = 32;
constexpr int NTHR    = 512;

typedef unsigned int u32x4 __attribute__((ext_vector_type(4)));

__device__ __forceinline__ float fast_tanh(float x) {
    // 1 - 2/(e^{2x}+1); saturates exactly at +-1 for large |x|
    float e = __expf(2.f * x);
    return 1.f - 2.f / (e + 1.f);
}

__device__ __forceinline__ float hsum4(const float4& v) {
    return (v.x + v.y) + (v.z + v.w);
}

// One 16B tagged-pair poll load observing the LLC (sc0 sc1), waited.
// Used inside a divergent do-while: lanes whose tags match exit the mask.
#define POLL16(reg, addr)                                               \
    do {                                                                \
        asm volatile("global_load_dwordx4 %0, %1, off sc0 sc1\n\t"      \
                     "s_waitcnt vmcnt(0)"                               \
                     : "=v"(reg) : "v"((unsigned long long)(addr))      \
                     : "memory");                                       \
        __builtin_amdgcn_sched_barrier(0);                              \
    } while (0)

__global__ __launch_bounds__(NTHR, 2)
void rnn_fused(const int* __restrict__ xs, const float* __restrict__ h0,
               const float* __restrict__ U, const float* __restrict__ W,
               const float* __restrict__ V, const float* __restrict__ bh,
               const float* __restrict__ by, float* __restrict__ out,
               unsigned long long* __restrict__ htag)
{
    const int b   = blockIdx.x;
    const int tid = threadIdx.x;
    const int w   = tid >> 6;      // wave 0..7
    const int l   = tid & 63;      // lane

    // h in LDS: 64 chunks x 16 floats; quad q of chunk c stored at dword
    // 16c + 4*(q ^ ((c>>1)&3)) (permutation inside the 64B chunk -> no
    // padding; spreads reads over all 32 banks).
    __shared__ float    hl[2][H_DIM];
    __shared__ unsigned s_ctr;      // wave-arrival counter (8 per step)

    if (tid == 0) s_ctr = 0;
    __syncthreads();                // once, to publish the zeroed counter

    // ---- W fragment: rows wr0..wr0+3, k in [16l, 16l+16) ----
    const int wr0 = b * 32 + w * 4;
    float4 wreg[4][4];
#pragma unroll
    for (int j = 0; j < 4; ++j)
#pragma unroll
        for (int q = 0; q < 4; ++q)
            wreg[j][q] = *(const float4*)(W + (size_t)(wr0 + j) * H_DIM + 16 * l + 4 * q);
    const float bh_r = bh[wr0 + (l & 3)];
    const int   urow = wr0 + (l & 3);

    // ---- V fragment: rows vr0, vr0+1, same k-chunk ----
    const int vr0 = b * 16 + w * 2;
    float4 vreg[2][4];
#pragma unroll
    for (int m = 0; m < 2; ++m)
#pragma unroll
        for (int q = 0; q < 4; ++q)
            vreg[m][q] = *(const float4*)(V + (size_t)(vr0 + m) * H_DIM + 16 * l + 4 * q);
    const float by_r = by[vr0 + (l & 1)];

    // ---- LDS addresses (dwords) ----
    int rdw[4];                    // lane reads chunk l, logical quads 0..3
#pragma unroll
    for (int q = 0; q < 4; ++q)
        rdw[q] = 16 * l + 4 * (q ^ ((l >> 1) & 3));
    const int c   = tid >> 3;                       // staged chunk
    const int qw  = (tid >> 1) & 3;                 // staged quad
    const int wdw = 16 * c + 4 * (qw ^ ((c >> 1) & 3)) + 2 * (tid & 1);  // 8B aligned

    const bool o1 = (l & 1) != 0, o2 = (l & 2) != 0;
    volatile unsigned* const vc = &s_ctr;

    for (int t = 0; t < T_STEPS; ++t) {
        const int sb = (~t) & 1;
        float* hb = hl[sb];

        // independent prefetch chain: xs[t] -> U gather (hidden under poll)
        const int   xt = xs[t];
        const float uv = U[(size_t)urow * D_DIM + xt];

        // ---- acquire h^{(t)}: divergent per-lane 16B tagged-pair poll ----
        float2 hpair;
        if (t == 0) {
            hpair = *(const float2*)(h0 + 2 * tid);
        } else {
            const unsigned want = (unsigned)(t - 1);
            const unsigned long long* pp =
                htag + (size_t)((t - 1) & 1) * H_DIM + 2 * tid;
            u32x4 q;
            do {
                POLL16(q, pp);                 // {val0, tag0, val1, tag1}
            } while (q.y != want || q.w != want);
            hpair = make_float2(__uint_as_float(q.x), __uint_as_float(q.z));
        }

        // ---- LDS stage + arrival-counter sync (replaces __syncthreads) ----
        *(float2*)&hb[wdw] = hpair;
        asm volatile("s_waitcnt lgkmcnt(0)" ::: "memory");  // slice before flag
        __builtin_amdgcn_sched_barrier(0);
        if (l == 0) atomicAdd(&s_ctr, 1u);
        const unsigned tgt = 8u * (unsigned)(t + 1);
        while (*vc < tgt) {}
        __builtin_amdgcn_sched_barrier(0);

        // ---- critical path: 16 h floats, 64 FMAs, fused select+reduce ----
        float4 h4[4];
#pragma unroll
        for (int q = 0; q < 4; ++q) h4[q] = *(const float4*)&hb[rdw[q]];

        float s[4];
#pragma unroll
        for (int j = 0; j < 4; ++j) {
            float4 a = make_float4(0.f, 0.f, 0.f, 0.f);
#pragma unroll
            for (int q = 0; q < 4; ++q) {
                a.x += wreg[j][q].x * h4[q].x;
                a.y += wreg[j][q].y * h4[q].y;
                a.z += wreg[j][q].z * h4[q].z;
                a.w += wreg[j][q].w * h4[q].w;
            }
            s[j] = hsum4(a);
        }
        // select+butterfly: lane l ends with full sum of row wr0 + (l&3)
        float A  = o1 ? s[1] : s[0], Ax = o1 ? s[0] : s[1];
        float B  = o1 ? s[3] : s[2], Bx = o1 ? s[2] : s[3];
        A += __shfl_xor(Ax, 1);
        B += __shfl_xor(Bx, 1);
        float Cv = o2 ? B : A, Cx = o2 ? A : B;
        Cv += __shfl_xor(Cx, 2);
        Cv += __shfl_xor(Cv, 4);
        Cv += __shfl_xor(Cv, 8);
        Cv += __shfl_xor(Cv, 16);
        Cv += __shfl_xor(Cv, 32);

        const float hv = fast_tanh(Cv + bh_r + uv);
        if (l < 4) {
            const unsigned long long pk =
                ((unsigned long long)(unsigned)t << 32) |
                (unsigned long long)__float_as_uint(hv);
            __hip_atomic_store(htag + (size_t)(t & 1) * H_DIM + wr0 + l, pk,
                               __ATOMIC_RELAXED, __HIP_MEMORY_SCOPE_AGENT);
        }
        __builtin_amdgcn_sched_barrier(0);   // publish must not sink below V

        // ---- hidden window: logits[t-1] from h4 registers (h^{(t)}) ----
        if (t > 0) {
            float sv[2];
#pragma unroll
            for (int m = 0; m < 2; ++m) {
                float4 a = make_float4(0.f, 0.f, 0.f, 0.f);
#pragma unroll
                for (int q = 0; q < 4; ++q) {
                    a.x += vreg[m][q].x * h4[q].x;
                    a.y += vreg[m][q].y * h4[q].y;
                    a.z += vreg[m][q].z * h4[q].z;
                    a.w += vreg[m][q].w * h4[q].w;
                }
                sv[m] = hsum4(a);
            }
            float P  = o1 ? sv[1] : sv[0], Px = o1 ? sv[0] : sv[1];
            P += __shfl_xor(Px, 1);
            P += __shfl_xor(P, 2);
            P += __shfl_xor(P, 4);
            P += __shfl_xor(P, 8);
            P += __shfl_xor(P, 16);
            P += __shfl_xor(P, 32);
            if (l < 2) out[(size_t)(t - 1) * O_DIM + vr0 + l] = P + by_r;
        }
    }

    // ---- epilogue: h_T (tag T-1, parity 1) -> out tail + logits[T-1] ----
    {
        const unsigned want = (unsigned)(T_STEPS - 1);
        const unsigned long long* pp =
            htag + (size_t)((T_STEPS - 1) & 1) * H_DIM + 2 * tid;
        u32x4 q;
        do {
            POLL16(q, pp);
        } while (q.y != want || q.w != want);
        float2 hpair = make_float2(__uint_as_float(q.x), __uint_as_float(q.z));
        if (b == 0)
            *(float2*)&out[(size_t)T_STEPS * O_DIM + 2 * tid] = hpair;

        float* hb = hl[1];             // free: loop's last stage used hl[0]
        *(float2*)&hb[wdw] = hpair;
        asm volatile("s_waitcnt lgkmcnt(0)" ::: "memory");
        __builtin_amdgcn_sched_barrier(0);
        if (l == 0) atomicAdd(&s_ctr, 1u);
        const unsigned tgt = 8u * (unsigned)(T_STEPS + 1);
        while (*vc < tgt) {}
        __builtin_amdgcn_sched_barrier(0);

        float4 h4[4];
#pragma unroll
        for (int qq = 0; qq < 4; ++qq) h4[qq] = *(const float4*)&hb[rdw[qq]];
        float sv[2];
#pragma unroll
        for (int m = 0; m < 2; ++m) {
            float4 a = make_float4(0.f, 0.f, 0.f, 0.f);
#pragma unroll
            for (int qq = 0; qq < 4; ++qq) {
                a.x += vreg[m][qq].x * h4[qq].x;
                a.y += vreg[m][qq].y * h4[qq].y;
                a.z += vreg[m][qq].z * h4[qq].z;
                a.w += vreg[m][qq].w * h4[qq].w;
            }
            sv[m] = hsum4(a);
        }
        float P  = o1 ? sv[1] : sv[0], Px = o1 ? sv[0] : sv[1];
        P += __shfl_xor(Px, 1);
        P += __shfl_xor(P, 2);
        P += __shfl_xor(P, 4);
        P += __shfl_xor(P, 8);
        P += __shfl_xor(P, 16);
        P += __shfl_xor(P, 32);
        if (l < 2) out[(size_t)(T_STEPS - 1) * O_DIM + vr0 + l] = P + by_r;
    }
}

extern "C" void kernel_launch(void* const* d_in, const int* in_sizes, int n_in,
                              void* d_out, int out_size, void* d_ws, size_t ws_size,
                              hipStream_t stream) {
    const int*   xs = (const int*)d_in[0];
    const float* h0 = (const float*)d_in[1];
    const float* U  = (const float*)d_in[2];
    const float* W  = (const float*)d_in[3];
    const float* V  = (const float*)d_in[4];
    const float* bh = (const float*)d_in[5];
    const float* by = (const float*)d_in[6];
    float* out = (float*)d_out;

    // ws: htag[2][1024] u64. Poison tag 0xAAAAAAAA never matches a step in
    // [0,16384); memset re-runs on every graph replay, clearing stale tags.
    unsigned long long* htag = (unsigned long long*)d_ws;
    hipMemsetAsync(d_ws, 0xAA, 2 * H_DIM * sizeof(unsigned long long), stream);

    rnn_fused<<<NBLK, NTHR, 0, stream>>>(xs, h0, U, W, V, bh, by, out, htag);
}

// Round 10
// 23512.671 us; speedup vs baseline: 1.7092x; 1.0585x over previous
//
#include <hip/hip_runtime.h>
#include <cstdint>

// TinyVanillaRNN: T=16384 sequential steps h = tanh(U[:,x_t] + W h + bh);
// logits[t] = V h_t + by. out = [logits (T*O) | h_T (H)], fp32.
//
// R13 = R3 verbatim (the measured best: 22865us). Final-state restore after
// five structured refutations of every alternative handoff design:
//   R7:  XCD-local sc0 polling       -> 10x worse (stale-L1 spins; no timely
//        sub-agent-scope visibility of remote stores on gfx950)
//   R8:  same-address poll pipelining -> +6% (MSHR-merged; sampling period
//        floor = one LLC-read RTT)
//   R9:  no-LDS full-vector gather    -> +76% (8x poll footprint, LLC
//        congestion + variance)
//   R10: poll preload + reorder       -> +63% (latency trapped in barrier
//        drain; poll churn)
//   R12: SW arrival-counter barrier   -> +9% (LDS spin costs more than the
//        HW barrier it replaced)
// Structural ceiling: 16384 sequential all-gathers of h (4KB) among 32 CUs
// through the memory-side coherence point. Step = store-commit (~500-700cy)
// + detect (~1000-1300cy, floor one LLC RTT) + distribute/compute (~600cy,
// partly overlapped) ~= 3350cy = 1395ns; T x 1395ns = 22.9ms. Latency-bound:
// HBM 0.4%, VALU 5%, occupancy irrelevant -- no counter-visible roofline,
// but every accessible term has been measured locally optimal.
//
// Structure (R3): 32 blocks x 512 threads. Thread = 4 W-rows x 16 k's (64 W
// floats in VGPRs) -> fetches only 16 h floats/step (4x ds_read_b128 at
// delivery floor). Reduce = 7-shuffle fused select+butterfly (row sum lands
// on lane l&3). V tiled identically (2 rows x 16 k's): logits reuse the
// matvec h registers -> zero extra LDS, computed in the post-publish window
// (hidden under next poll RTT). Handoff: tagged u64 (step<<32 | f32 bits),
// parity double buffer, relaxed agent atomics; all 512 threads poll 2 words.

constexpr int T_STEPS = 16384;
constexpr int D_DIM   = 512;
constexpr int H_DIM   = 1024;
constexpr int O_DIM   = 512;
constexpr int NBLK    = 32;
constexpr int NTHR    = 512;

__device__ __forceinline__ float fast_tanh(float x) {
    // 1 - 2/(e^{2x}+1); saturates exactly at +-1 for large |x|
    float e = __expf(2.f * x);
    return 1.f - 2.f / (e + 1.f);
}

__device__ __forceinline__ float hsum4(const float4& v) {
    return (v.x + v.y) + (v.z + v.w);
}

__global__ __launch_bounds__(NTHR, 2)
void rnn_fused(const int* __restrict__ xs, const float* __restrict__ h0,
               const float* __restrict__ U, const float* __restrict__ W,
               const float* __restrict__ V, const float* __restrict__ bh,
               const float* __restrict__ by, float* __restrict__ out,
               unsigned long long* __restrict__ htag)
{
    const int b   = blockIdx.x;
    const int tid = threadIdx.x;
    const int w   = tid >> 6;      // wave 0..7
    const int l   = tid & 63;      // lane

    // h in LDS: 64 chunks x 16 floats; quad q of chunk c stored at dword
    // 16c + 4*(q ^ ((c>>1)&3))  (swizzle is a permutation inside the 64B
    // chunk -> no padding; spreads reads over all 32 banks).
    __shared__ float hl[2][H_DIM];

    // ---- W fragment: rows wr0..wr0+3, k in [16l, 16l+16) ----
    const int wr0 = b * 32 + w * 4;
    float4 wreg[4][4];
#pragma unroll
    for (int j = 0; j < 4; ++j)
#pragma unroll
        for (int q = 0; q < 4; ++q)
            wreg[j][q] = *(const float4*)(W + (size_t)(wr0 + j) * H_DIM + 16 * l + 4 * q);
    const float bh_r = bh[wr0 + (l & 3)];
    const int   urow = wr0 + (l & 3);

    // ---- V fragment: rows vr0, vr0+1, same k-chunk ----
    const int vr0 = b * 16 + w * 2;
    float4 vreg[2][4];
#pragma unroll
    for (int m = 0; m < 2; ++m)
#pragma unroll
        for (int q = 0; q < 4; ++q)
            vreg[m][q] = *(const float4*)(V + (size_t)(vr0 + m) * H_DIM + 16 * l + 4 * q);
    const float by_r = by[vr0 + (l & 1)];

    // ---- LDS addresses (dwords) ----
    int rdw[4];                    // lane reads chunk l, logical quads 0..3
#pragma unroll
    for (int q = 0; q < 4; ++q)
        rdw[q] = 16 * l + 4 * (q ^ ((l >> 1) & 3));
    const int c   = tid >> 3;                       // staged chunk
    const int qw  = (tid >> 1) & 3;                 // staged quad
    const int wdw = 16 * c + 4 * (qw ^ ((c >> 1) & 3)) + 2 * (tid & 1);  // even -> 8B aligned

    const bool o1 = (l & 1) != 0, o2 = (l & 2) != 0;

    for (int t = 0; t < T_STEPS; ++t) {
        const int sb = (~t) & 1;
        float* hb = hl[sb];

        // independent prefetch chain: xs[t] -> U gather (hidden under poll)
        const int   xt = xs[t];
        const float uv = U[(size_t)urow * D_DIM + xt];

        // ---- acquire h^{(t)}: all 512 threads poll 2 tagged words ----
        float2 hpair;
        if (t == 0) {
            hpair = *(const float2*)(h0 + 2 * tid);
        } else {
            const unsigned want = (unsigned)(t - 1);
            const unsigned long long* pp = htag + (size_t)((t - 1) & 1) * H_DIM + 2 * tid;
            unsigned long long q0, q1;
            do {
                q0 = __hip_atomic_load(pp + 0, __ATOMIC_RELAXED, __HIP_MEMORY_SCOPE_AGENT);
                q1 = __hip_atomic_load(pp + 1, __ATOMIC_RELAXED, __HIP_MEMORY_SCOPE_AGENT);
            } while ((unsigned)(q0 >> 32) != want || (unsigned)(q1 >> 32) != want);
            hpair = make_float2(__uint_as_float((unsigned)q0),
                                __uint_as_float((unsigned)q1));
        }
        *(float2*)&hb[wdw] = hpair;
        __syncthreads();

        // ---- critical path: 16 h floats, 64 FMAs, fused select+reduce ----
        float4 h4[4];
#pragma unroll
        for (int q = 0; q < 4; ++q) h4[q] = *(const float4*)&hb[rdw[q]];

        float s[4];
#pragma unroll
        for (int j = 0; j < 4; ++j) {
            float4 a = make_float4(0.f, 0.f, 0.f, 0.f);
#pragma unroll
            for (int q = 0; q < 4; ++q) {
                a.x += wreg[j][q].x * h4[q].x;
                a.y += wreg[j][q].y * h4[q].y;
                a.z += wreg[j][q].z * h4[q].z;
                a.w += wreg[j][q].w * h4[q].w;
            }
            s[j] = hsum4(a);
        }
        // select+butterfly: lane l ends with full sum of row wr0 + (l&3)
        float A  = o1 ? s[1] : s[0], Ax = o1 ? s[0] : s[1];
        float B  = o1 ? s[3] : s[2], Bx = o1 ? s[2] : s[3];
        A += __shfl_xor(Ax, 1);
        B += __shfl_xor(Bx, 1);
        float Cv = o2 ? B : A, Cx = o2 ? A : B;
        Cv += __shfl_xor(Cx, 2);
        Cv += __shfl_xor(Cv, 4);
        Cv += __shfl_xor(Cv, 8);
        Cv += __shfl_xor(Cv, 16);
        Cv += __shfl_xor(Cv, 32);

        const float hv = fast_tanh(Cv + bh_r + uv);
        if (l < 4) {
            const unsigned long long pk =
                ((unsigned long long)(unsigned)t << 32) | (unsigned long long)__float_as_uint(hv);
            __hip_atomic_store(htag + (size_t)(t & 1) * H_DIM + wr0 + l, pk,
                               __ATOMIC_RELAXED, __HIP_MEMORY_SCOPE_AGENT);
        }

        // ---- hidden window: logits[t-1] from h4 registers (h^{(t)}) ----
        if (t > 0) {
            float sv[2];
#pragma unroll
            for (int m = 0; m < 2; ++m) {
                float4 a = make_float4(0.f, 0.f, 0.f, 0.f);
#pragma unroll
                for (int q = 0; q < 4; ++q) {
                    a.x += vreg[m][q].x * h4[q].x;
                    a.y += vreg[m][q].y * h4[q].y;
                    a.z += vreg[m][q].z * h4[q].z;
                    a.w += vreg[m][q].w * h4[q].w;
                }
                sv[m] = hsum4(a);
            }
            float P  = o1 ? sv[1] : sv[0], Px = o1 ? sv[0] : sv[1];
            P += __shfl_xor(Px, 1);
            P += __shfl_xor(P, 2);
            P += __shfl_xor(P, 4);
            P += __shfl_xor(P, 8);
            P += __shfl_xor(P, 16);
            P += __shfl_xor(P, 32);
            if (l < 2) out[(size_t)(t - 1) * O_DIM + vr0 + l] = P + by_r;
        }
    }

    // ---- epilogue: h_T (tag T-1, parity 1) -> out tail + logits[T-1] ----
    {
        const unsigned want = (unsigned)(T_STEPS - 1);
        const unsigned long long* pp = htag + (size_t)((T_STEPS - 1) & 1) * H_DIM + 2 * tid;
        unsigned long long q0, q1;
        do {
            q0 = __hip_atomic_load(pp + 0, __ATOMIC_RELAXED, __HIP_MEMORY_SCOPE_AGENT);
            q1 = __hip_atomic_load(pp + 1, __ATOMIC_RELAXED, __HIP_MEMORY_SCOPE_AGENT);
        } while ((unsigned)(q0 >> 32) != want || (unsigned)(q1 >> 32) != want);
        float2 hpair = make_float2(__uint_as_float((unsigned)q0),
                                   __uint_as_float((unsigned)q1));
        if (b == 0)
            *(float2*)&out[(size_t)T_STEPS * O_DIM + 2 * tid] = hpair;

        float* hb = hl[1];             // free: loop's last stage used hl[0]
        *(float2*)&hb[wdw] = hpair;
        __syncthreads();
        float4 h4[4];
#pragma unroll
        for (int q = 0; q < 4; ++q) h4[q] = *(const float4*)&hb[rdw[q]];
        float sv[2];
#pragma unroll
        for (int m = 0; m < 2; ++m) {
            float4 a = make_float4(0.f, 0.f, 0.f, 0.f);
#pragma unroll
            for (int q = 0; q < 4; ++q) {
                a.x += vreg[m][q].x * h4[q].x;
                a.y += vreg[m][q].y * h4[q].y;
                a.z += vreg[m][q].z * h4[q].z;
                a.w += vreg[m][q].w * h4[q].w;
            }
            sv[m] = hsum4(a);
        }
        float P  = o1 ? sv[1] : sv[0], Px = o1 ? sv[0] : sv[1];
        P += __shfl_xor(Px, 1);
        P += __shfl_xor(P, 2);
        P += __shfl_xor(P, 4);
        P += __shfl_xor(P, 8);
        P += __shfl_xor(P, 16);
        P += __shfl_xor(P, 32);
        if (l < 2) out[(size_t)(T_STEPS - 1) * O_DIM + vr0 + l] = P + by_r;
    }
}

extern "C" void kernel_launch(void* const* d_in, const int* in_sizes, int n_in,
                              void* d_out, int out_size, void* d_ws, size_t ws_size,
                              hipStream_t stream) {
    const int*   xs = (const int*)d_in[0];
    const float* h0 = (const float*)d_in[1];
    const float* U  = (const float*)d_in[2];
    const float* W  = (const float*)d_in[3];
    const float* V  = (const float*)d_in[4];
    const float* bh = (const float*)d_in[5];
    const float* by = (const float*)d_in[6];
    float* out = (float*)d_out;

    // ws: htag[2][1024] u64. Poison tag 0xAAAAAAAA never matches a step in
    // [0,16384); memset re-runs on every graph replay, clearing stale tags.
    unsigned long long* htag = (unsigned long long*)d_ws;
    hipMemsetAsync(d_ws, 0xAA, 2 * H_DIM * sizeof(unsigned long long), stream);

    rnn_fused<<<NBLK, NTHR, 0, stream>>>(xs, h0, U, W, V, bh, by, out, htag);
}